// Round 1
// baseline (2776.129 us; speedup 1.0000x reference)
//
#include <hip/hip_runtime.h>
#include <math.h>

#define BB 16
#define TT 512
#define DD 1024
#define HH 16
#define DKK 64
#define WIN 128
#define MAXLEN 512

// ---------------- GEMM 1: qkv = x @ Wqkv + bqkv, scatter to q,k,v [B,H,T,DK] ----------------
__global__ __launch_bounds__(256) void qkv_gemm(const float* __restrict__ x,
                                                const float* __restrict__ W,
                                                const float* __restrict__ bias,
                                                float* __restrict__ q,
                                                float* __restrict__ k,
                                                float* __restrict__ v)
{
    const int K = DD;        // 1024
    const int N = 3 * DD;    // 3072
    __shared__ float As[16][68];   // [k][m], padded stride 68
    __shared__ float Bs[16][68];   // [k][n]
    const int tid = threadIdx.x;
    const int m0 = blockIdx.y * 64;
    const int n0 = blockIdx.x * 64;
    const int tx = tid & 15, ty = tid >> 4;
    const int ac = tid & 15, ar = tid >> 4;   // A load: k=ac, m=ar+16*l
    const int bc = tid & 63, br = tid >> 6;   // B load: n=bc, k=br+4*l

    float acc[4][4] = {};

    for (int k0 = 0; k0 < K; k0 += 16) {
#pragma unroll
        for (int l = 0; l < 4; ++l)
            As[ac][ar + 16 * l] = x[(size_t)(m0 + ar + 16 * l) * K + k0 + ac];
#pragma unroll
        for (int l = 0; l < 4; ++l)
            Bs[br + 4 * l][bc] = W[(size_t)(k0 + br + 4 * l) * N + n0 + bc];
        __syncthreads();
#pragma unroll
        for (int kk = 0; kk < 16; ++kk) {
            float4 a = *(const float4*)&As[kk][ty * 4];
            float4 b = *(const float4*)&Bs[kk][tx * 4];
            float av[4] = {a.x, a.y, a.z, a.w};
            float bv[4] = {b.x, b.y, b.z, b.w};
#pragma unroll
            for (int i = 0; i < 4; ++i)
#pragma unroll
                for (int j = 0; j < 4; ++j)
                    acc[i][j] += av[i] * bv[j];
        }
        __syncthreads();
    }

#pragma unroll
    for (int i = 0; i < 4; ++i) {
        const int m = m0 + ty * 4 + i;
        const int bidx = m >> 9;          // /T
        const int t = m & (TT - 1);
#pragma unroll
        for (int j = 0; j < 4; ++j) {
            const int n = n0 + tx * 4 + j;
            const float val = acc[i][j] + bias[n];
            const int sel = n >> 10;      // 0=q 1=k 2=v
            const int d = n & (DD - 1);
            const int h = d >> 6;
            const int dk = d & (DKK - 1);
            float* dst = (sel == 0) ? q : (sel == 1) ? k : v;
            dst[((((size_t)bidx * HH + h) * TT + t) * DKK) + dk] = val;
        }
    }
}

// ---------------- Attention: one block per (b,h,i) ----------------
__global__ __launch_bounds__(256) void attn_kernel(const float* __restrict__ q,
                                                   const float* __restrict__ k,
                                                   const float* __restrict__ v,
                                                   const float* __restrict__ rel,
                                                   float* __restrict__ attn_out,
                                                   float* __restrict__ ctx)
{
    const int i = blockIdx.x;
    const int h = blockIdx.y;
    const int b = blockIdx.z;
    const int tid = threadIdx.x;

    __shared__ float q_s[DKK];
    __shared__ float p_s[TT];
    __shared__ float red[256];

    const size_t bh = (size_t)b * HH + h;
    const float* kbase = k + bh * TT * DKK;
    const float* vbase = v + bh * TT * DKK;
    const float* qrow  = q + (bh * TT + i) * DKK;

    if (tid < DKK) q_s[tid] = qrow[tid];
    __syncthreads();

    int j0 = i - WIN; if (j0 < 0) j0 = 0;
    int j1 = i + WIN; if (j1 > TT - 1) j1 = TT - 1;

    float s_local[2];
#pragma unroll
    for (int p = 0; p < 2; ++p) {
        const int j = tid + p * 256;
        float s = -INFINITY;
        if (j >= j0 && j <= j1) {
            const float* krow = kbase + (size_t)j * DKK;
            float acc = 0.f;
#pragma unroll
            for (int d4 = 0; d4 < 16; ++d4) {
                float4 kv4 = *(const float4*)&krow[d4 * 4];
                acc += q_s[d4 * 4 + 0] * kv4.x + q_s[d4 * 4 + 1] * kv4.y +
                       q_s[d4 * 4 + 2] * kv4.z + q_s[d4 * 4 + 3] * kv4.w;
            }
            s = acc * 0.125f + rel[(size_t)(j - i + MAXLEN - 1) * HH + h];
        }
        s_local[p] = s;
    }

    // block max
    red[tid] = fmaxf(s_local[0], s_local[1]);
    __syncthreads();
    for (int st = 128; st > 0; st >>= 1) {
        if (tid < st) red[tid] = fmaxf(red[tid], red[tid + st]);
        __syncthreads();
    }
    const float m = red[0];
    __syncthreads();

    float e_local[2];
#pragma unroll
    for (int p = 0; p < 2; ++p)
        e_local[p] = __expf(s_local[p] - m);   // -inf -> 0

    // block sum
    red[tid] = e_local[0] + e_local[1];
    __syncthreads();
    for (int st = 128; st > 0; st >>= 1) {
        if (tid < st) red[tid] += red[tid + st];
        __syncthreads();
    }
    const float inv = 1.0f / red[0];
    __syncthreads();

    float* arow = attn_out + (bh * TT + i) * TT;
#pragma unroll
    for (int p = 0; p < 2; ++p) {
        const int j = tid + p * 256;
        const float val = e_local[p] * inv;
        arow[j] = val;
        p_s[j] = val;
    }
    __syncthreads();

    // ctx[d] = sum_j p[j] * v[j][d]; 4 waves split j, 64 lanes = d
    const int w = tid >> 6;
    const int lane = tid & 63;
    float partial = 0.f;
    for (int j = j0 + w; j <= j1; j += 4)
        partial += p_s[j] * vbase[(size_t)j * DKK + lane];
    red[w * 64 + lane] = partial;
    __syncthreads();
    if (tid < DKK) {
        const float c = red[tid] + red[64 + tid] + red[128 + tid] + red[192 + tid];
        ctx[(((size_t)b * TT + i) * HH + h) * DKK + tid] = c;
    }
}

// ---------------- GEMM 2: out = ctx @ Wo + bo ----------------
__global__ __launch_bounds__(256) void out_gemm(const float* __restrict__ A,
                                                const float* __restrict__ W,
                                                const float* __restrict__ bias,
                                                float* __restrict__ out)
{
    const int K = DD;   // 1024
    const int N = DD;   // 1024
    __shared__ float As[16][68];
    __shared__ float Bs[16][68];
    const int tid = threadIdx.x;
    const int m0 = blockIdx.y * 64;
    const int n0 = blockIdx.x * 64;
    const int tx = tid & 15, ty = tid >> 4;
    const int ac = tid & 15, ar = tid >> 4;
    const int bc = tid & 63, br = tid >> 6;

    float acc[4][4] = {};

    for (int k0 = 0; k0 < K; k0 += 16) {
#pragma unroll
        for (int l = 0; l < 4; ++l)
            As[ac][ar + 16 * l] = A[(size_t)(m0 + ar + 16 * l) * K + k0 + ac];
#pragma unroll
        for (int l = 0; l < 4; ++l)
            Bs[br + 4 * l][bc] = W[(size_t)(k0 + br + 4 * l) * N + n0 + bc];
        __syncthreads();
#pragma unroll
        for (int kk = 0; kk < 16; ++kk) {
            float4 a = *(const float4*)&As[kk][ty * 4];
            float4 b = *(const float4*)&Bs[kk][tx * 4];
            float av[4] = {a.x, a.y, a.z, a.w};
            float bv[4] = {b.x, b.y, b.z, b.w};
#pragma unroll
            for (int i = 0; i < 4; ++i)
#pragma unroll
                for (int j = 0; j < 4; ++j)
                    acc[i][j] += av[i] * bv[j];
        }
        __syncthreads();
    }

#pragma unroll
    for (int i = 0; i < 4; ++i) {
        const int m = m0 + ty * 4 + i;
#pragma unroll
        for (int j = 0; j < 4; ++j) {
            const int n = n0 + tx * 4 + j;
            out[(size_t)m * N + n] = acc[i][j] + bias[n];
        }
    }
}

extern "C" void kernel_launch(void* const* d_in, const int* in_sizes, int n_in,
                              void* d_out, int out_size, void* d_ws, size_t ws_size,
                              hipStream_t stream)
{
    const float* x    = (const float*)d_in[0];
    const float* Wqkv = (const float*)d_in[1];
    const float* bqkv = (const float*)d_in[2];
    const float* Wo   = (const float*)d_in[3];
    const float* bo   = (const float*)d_in[4];
    const float* rel  = (const float*)d_in[5];

    float* out  = (float*)d_out;                       // [B,T,D]
    float* attn = out + (size_t)BB * TT * DD;          // [B,H,T,T]

    const size_t per = (size_t)BB * HH * TT * DKK;     // 8,388,608 floats
    float* q   = (float*)d_ws;
    float* k   = q + per;
    float* v   = k + per;
    float* ctx = v + per;                              // [B,T,H,DK]

    // QKV projection + head split
    qkv_gemm<<<dim3(3 * DD / 64, BB * TT / 64), 256, 0, stream>>>(x, Wqkv, bqkv, q, k, v);

    // windowed attention + bias + softmax; writes attn (incl. masked zeros) and ctx
    attn_kernel<<<dim3(TT, HH, BB), 256, 0, stream>>>(q, k, v, rel, attn, ctx);

    // output projection
    out_gemm<<<dim3(DD / 64, BB * TT / 64), 256, 0, stream>>>(ctx, Wo, bo, out);
}

// Round 2
// 1473.319 us; speedup vs baseline: 1.8843x; 1.8843x over previous
//
#include <hip/hip_runtime.h>
#include <math.h>

#define BB 16
#define TT 512
#define DD 1024
#define HH 16
#define DKK 64
#define WIN 128
#define MAXLEN 512

#define TILE_M 64
#define JSPAN 320
#define NCHUNK 5
#define LSTR 68   // padded LDS row stride (floats), 16B-aligned

// ---------------- GEMM 1: qkv = x @ Wqkv + bqkv, scatter to q,k,v [B,H,T,DK] ----------------
__global__ __launch_bounds__(256) void qkv_gemm(const float* __restrict__ x,
                                                const float* __restrict__ W,
                                                const float* __restrict__ bias,
                                                float* __restrict__ q,
                                                float* __restrict__ k,
                                                float* __restrict__ v)
{
    const int K = DD;        // 1024
    const int N = 3 * DD;    // 3072
    __shared__ float As[16][68];   // [k][m]
    __shared__ float Bs[16][68];   // [k][n]
    const int tid = threadIdx.x;
    const int m0 = blockIdx.y * 64;
    const int n0 = blockIdx.x * 64;
    const int tx = tid & 15, ty = tid >> 4;
    const int ac = tid & 15, ar = tid >> 4;
    const int bc = tid & 63, br = tid >> 6;

    float acc[4][4] = {};

    for (int k0 = 0; k0 < K; k0 += 16) {
#pragma unroll
        for (int l = 0; l < 4; ++l)
            As[ac][ar + 16 * l] = x[(size_t)(m0 + ar + 16 * l) * K + k0 + ac];
#pragma unroll
        for (int l = 0; l < 4; ++l)
            Bs[br + 4 * l][bc] = W[(size_t)(k0 + br + 4 * l) * N + n0 + bc];
        __syncthreads();
#pragma unroll
        for (int kk = 0; kk < 16; ++kk) {
            float4 a = *(const float4*)&As[kk][ty * 4];
            float4 b = *(const float4*)&Bs[kk][tx * 4];
            float av[4] = {a.x, a.y, a.z, a.w};
            float bv[4] = {b.x, b.y, b.z, b.w};
#pragma unroll
            for (int i = 0; i < 4; ++i)
#pragma unroll
                for (int j = 0; j < 4; ++j)
                    acc[i][j] += av[i] * bv[j];
        }
        __syncthreads();
    }

#pragma unroll
    for (int i = 0; i < 4; ++i) {
        const int m = m0 + ty * 4 + i;
        const int bidx = m >> 9;
        const int t = m & (TT - 1);
#pragma unroll
        for (int j = 0; j < 4; ++j) {
            const int n = n0 + tx * 4 + j;
            const float val = acc[i][j] + bias[n];
            const int sel = n >> 10;
            const int d = n & (DD - 1);
            const int h = d >> 6;
            const int dk = d & (DKK - 1);
            float* dst = (sel == 0) ? q : (sel == 1) ? k : v;
            dst[((((size_t)bidx * HH + h) * TT + t) * DKK) + dk] = val;
        }
    }
}

// ---------------- Fused windowed attention, flash-style, 64-row tiles ----------------
// block = 256 threads, grid = (T/64, H, B)
__global__ __launch_bounds__(256) void attn_fused(const float* __restrict__ q,
                                                  const float* __restrict__ k,
                                                  const float* __restrict__ v,
                                                  const float* __restrict__ rel,
                                                  float* __restrict__ attn_out,
                                                  float* __restrict__ ctx)
{
    const int it = blockIdx.x;
    const int h  = blockIdx.y;
    const int b  = blockIdx.z;
    const int i0 = it * TILE_M;
    int jbase = i0 - WIN; if (jbase < 0) jbase = 0; if (jbase > TT - JSPAN) jbase = TT - JSPAN;

    const int tid = threadIdx.x;
    const int tx = tid & 15, ty = tid >> 4;

    // LDS: buf0 = q^T (phase1) / P^T (phase3); buf1 = k^T (phase1) / V (phase3); bias row
    __shared__ float smem[2 * TILE_M * LSTR + 1024];
    float* buf0   = smem;                       // [64][LSTR]
    float* buf1   = smem + TILE_M * LSTR;       // [64][LSTR]
    float* bias_s = smem + 2 * TILE_M * LSTR;   // [1023]

    const size_t bh = (size_t)b * HH + h;
    const float* qb = q + (bh * TT + i0) * DKK;
    const float* kb = k + bh * TT * DKK;
    const float* vb = v + bh * TT * DKK;
    float* arow = attn_out + (bh * TT + i0) * TT;

    // ---- zero-fill attn outside [jbase, jbase+JSPAN) : 64 rows x 192 cols ----
    {
        const float4 z = make_float4(0.f, 0.f, 0.f, 0.f);
        for (int idx = tid; idx < TILE_M * 48; idx += 256) {
            const int r  = idx / 48;
            const int c4 = idx - r * 48;
            const int col = (c4 * 4 < jbase) ? c4 * 4 : c4 * 4 + JSPAN;
            *(float4*)&arow[(size_t)r * TT + col] = z;
        }
    }

    // ---- load rel-bias slice for this head ----
    for (int idx = tid; idx < 2 * MAXLEN - 1; idx += 256)
        bias_s[idx] = rel[(size_t)idx * HH + h];

    // ---- load q^T into buf0: buf0[d][i] = q[i0+i][d] ----
    {
        const int d = tid & 63, r0 = tid >> 6;
#pragma unroll
        for (int ii = 0; ii < 16; ++ii) {
            const int i = r0 + ii * 4;
            buf0[d * LSTR + i] = qb[(size_t)i * DKK + d];
        }
    }
    __syncthreads();

    // ---- phase 1: scores for 5 chunks, held in registers ----
    float s[NCHUNK][4][4];
#pragma unroll 1
    for (int c = 0; c < NCHUNK; ++c) {
        if (c > 0) __syncthreads();           // previous chunk's GEMM reads of buf1 done
        {
            const int d = tid & 63, r0 = tid >> 6;
#pragma unroll
            for (int jj = 0; jj < 16; ++jj) {
                const int j = r0 + jj * 4;
                buf1[d * LSTR + j] = kb[(size_t)(jbase + c * 64 + j) * DKK + d];
            }
        }
        __syncthreads();
        float acc[4][4] = {};
#pragma unroll
        for (int kk = 0; kk < 64; ++kk) {
            float4 a  = *(const float4*)&buf0[kk * LSTR + ty * 4];
            float4 b4 = *(const float4*)&buf1[kk * LSTR + tx * 4];
            float av[4] = {a.x, a.y, a.z, a.w};
            float bv[4] = {b4.x, b4.y, b4.z, b4.w};
#pragma unroll
            for (int r = 0; r < 4; ++r)
#pragma unroll
                for (int cc = 0; cc < 4; ++cc)
                    acc[r][cc] += av[r] * bv[cc];
        }
#pragma unroll
        for (int r = 0; r < 4; ++r) {
            const int i = i0 + ty * 4 + r;
#pragma unroll
            for (int cc = 0; cc < 4; ++cc) {
                const int j = jbase + c * 64 + tx * 4 + cc;
                const int d = j - i;
                const float val = acc[r][cc] * 0.125f + bias_s[d + MAXLEN - 1];
                s[c][r][cc] = (d >= -WIN && d <= WIN) ? val : -INFINITY;
            }
        }
    }

    // ---- softmax across the 5 chunks (shuffle-only row reductions over tx) ----
    float mrow[4], sumr[4];
#pragma unroll
    for (int r = 0; r < 4; ++r) {
        float m = -INFINITY;
#pragma unroll
        for (int c = 0; c < NCHUNK; ++c)
#pragma unroll
            for (int cc = 0; cc < 4; ++cc) m = fmaxf(m, s[c][r][cc]);
        mrow[r] = m;
    }
#pragma unroll
    for (int off = 1; off < 16; off <<= 1)
#pragma unroll
        for (int r = 0; r < 4; ++r)
            mrow[r] = fmaxf(mrow[r], __shfl_xor(mrow[r], off));
#pragma unroll
    for (int r = 0; r < 4; ++r) sumr[r] = 0.f;
#pragma unroll
    for (int c = 0; c < NCHUNK; ++c)
#pragma unroll
        for (int r = 0; r < 4; ++r)
#pragma unroll
            for (int cc = 0; cc < 4; ++cc) {
                const float e = __expf(s[c][r][cc] - mrow[r]);
                s[c][r][cc] = e;
                sumr[r] += e;
            }
#pragma unroll
    for (int off = 1; off < 16; off <<= 1)
#pragma unroll
        for (int r = 0; r < 4; ++r)
            sumr[r] += __shfl_xor(sumr[r], off);
    float invr[4];
#pragma unroll
    for (int r = 0; r < 4; ++r) invr[r] = 1.0f / sumr[r];
#pragma unroll
    for (int c = 0; c < NCHUNK; ++c)
#pragma unroll
        for (int r = 0; r < 4; ++r)
#pragma unroll
            for (int cc = 0; cc < 4; ++cc)
                s[c][r][cc] *= invr[r];

    // ---- phase 3: write attn + PV accumulate ----
    float o[4][4] = {};
#pragma unroll 1
    for (int c = 0; c < NCHUNK; ++c) {
        __syncthreads();   // previous GEMM reads (or phase-1 buf0 reads) done
        // write P^T into buf0 + attn row to global
#pragma unroll
        for (int r = 0; r < 4; ++r) {
            float4 pv = make_float4(s[c][r][0], s[c][r][1], s[c][r][2], s[c][r][3]);
            *(float4*)&arow[(size_t)(ty * 4 + r) * TT + jbase + c * 64 + tx * 4] = pv;
#pragma unroll
            for (int cc = 0; cc < 4; ++cc)
                buf0[(tx * 4 + cc) * LSTR + ty * 4 + r] = s[c][r][cc];
        }
        // load V chunk into buf1 (natural layout [j][d])
        {
            const int d4 = (tid & 15) * 4, r0 = tid >> 4;
#pragma unroll
            for (int jj = 0; jj < 4; ++jj) {
                const int j = r0 + jj * 16;
                *(float4*)&buf1[j * LSTR + d4] =
                    *(const float4*)&vb[(size_t)(jbase + c * 64 + j) * DKK + d4];
            }
        }
        __syncthreads();
#pragma unroll
        for (int kk = 0; kk < 64; ++kk) {
            float4 a  = *(const float4*)&buf0[kk * LSTR + ty * 4];
            float4 b4 = *(const float4*)&buf1[kk * LSTR + tx * 4];
            float av[4] = {a.x, a.y, a.z, a.w};
            float bv[4] = {b4.x, b4.y, b4.z, b4.w};
#pragma unroll
            for (int r = 0; r < 4; ++r)
#pragma unroll
                for (int cc = 0; cc < 4; ++cc)
                    o[r][cc] += av[r] * bv[cc];
        }
    }

    // ---- epilogue: ctx[b, i, h, d] ----
#pragma unroll
    for (int r = 0; r < 4; ++r) {
        float4 ov = make_float4(o[r][0], o[r][1], o[r][2], o[r][3]);
        *(float4*)&ctx[(((size_t)b * TT + i0 + ty * 4 + r) * HH + h) * DKK + tx * 4] = ov;
    }
}

// ---------------- GEMM 2: out = ctx @ Wo + bo ----------------
__global__ __launch_bounds__(256) void out_gemm(const float* __restrict__ A,
                                                const float* __restrict__ W,
                                                const float* __restrict__ bias,
                                                float* __restrict__ out)
{
    const int K = DD;
    const int N = DD;
    __shared__ float As[16][68];
    __shared__ float Bs[16][68];
    const int tid = threadIdx.x;
    const int m0 = blockIdx.y * 64;
    const int n0 = blockIdx.x * 64;
    const int tx = tid & 15, ty = tid >> 4;
    const int ac = tid & 15, ar = tid >> 4;
    const int bc = tid & 63, br = tid >> 6;

    float acc[4][4] = {};

    for (int k0 = 0; k0 < K; k0 += 16) {
#pragma unroll
        for (int l = 0; l < 4; ++l)
            As[ac][ar + 16 * l] = A[(size_t)(m0 + ar + 16 * l) * K + k0 + ac];
#pragma unroll
        for (int l = 0; l < 4; ++l)
            Bs[br + 4 * l][bc] = W[(size_t)(k0 + br + 4 * l) * N + n0 + bc];
        __syncthreads();
#pragma unroll
        for (int kk = 0; kk < 16; ++kk) {
            float4 a = *(const float4*)&As[kk][ty * 4];
            float4 b = *(const float4*)&Bs[kk][tx * 4];
            float av[4] = {a.x, a.y, a.z, a.w};
            float bv[4] = {b.x, b.y, b.z, b.w};
#pragma unroll
            for (int i = 0; i < 4; ++i)
#pragma unroll
                for (int j = 0; j < 4; ++j)
                    acc[i][j] += av[i] * bv[j];
        }
        __syncthreads();
    }

#pragma unroll
    for (int i = 0; i < 4; ++i) {
        const int m = m0 + ty * 4 + i;
#pragma unroll
        for (int j = 0; j < 4; ++j) {
            const int n = n0 + tx * 4 + j;
            out[(size_t)m * N + n] = acc[i][j] + bias[n];
        }
    }
}

extern "C" void kernel_launch(void* const* d_in, const int* in_sizes, int n_in,
                              void* d_out, int out_size, void* d_ws, size_t ws_size,
                              hipStream_t stream)
{
    const float* x    = (const float*)d_in[0];
    const float* Wqkv = (const float*)d_in[1];
    const float* bqkv = (const float*)d_in[2];
    const float* Wo   = (const float*)d_in[3];
    const float* bo   = (const float*)d_in[4];
    const float* rel  = (const float*)d_in[5];

    float* out  = (float*)d_out;
    float* attn = out + (size_t)BB * TT * DD;

    const size_t per = (size_t)BB * HH * TT * DKK;
    float* q   = (float*)d_ws;
    float* k   = q + per;
    float* v   = k + per;
    float* ctx = v + per;

    qkv_gemm<<<dim3(3 * DD / 64, BB * TT / 64), 256, 0, stream>>>(x, Wqkv, bqkv, q, k, v);
    attn_fused<<<dim3(TT / TILE_M, HH, BB), 256, 0, stream>>>(q, k, v, rel, attn, ctx);
    out_gemm<<<dim3(DD / 64, BB * TT / 64), 256, 0, stream>>>(ctx, Wo, bo, out);
}

// Round 3
// 835.873 us; speedup vs baseline: 3.3212x; 1.7626x over previous
//
#include <hip/hip_runtime.h>
#include <math.h>

typedef unsigned short ushort_t;
typedef __bf16 bf16x8 __attribute__((ext_vector_type(8)));
typedef float f32x4 __attribute__((ext_vector_type(4)));

#define BB 16
#define TT 512
#define DD 1024
#define HH 16
#define DKK 64
#define WIN 128
#define MAXLEN 512

#define TILE_M 64
#define JSPAN 320
#define NCHUNK 5
#define LSTR 68

#define LK 40   // LDS row stride in ushorts for MFMA tiles (32 + 8 pad, 80B: 16B-aligned rows, all-32-bank coverage)

// ---------------- fp32 -> bf16 hi/lo split helpers ----------------
__device__ __forceinline__ ushort_t f2bf(float f) {
    union { float f; unsigned u; } x; x.f = f;
    unsigned r = x.u + 0x7fffu + ((x.u >> 16) & 1u);   // RTN-even
    return (ushort_t)(r >> 16);
}
__device__ __forceinline__ float bf2f(ushort_t h) {
    union { unsigned u; float f; } x; x.u = ((unsigned)h) << 16;
    return x.f;
}

// ---------------- conversion: A [M][K] fp32 -> hi/lo bf16 same layout ----------------
__global__ __launch_bounds__(256) void conv_split(const float* __restrict__ src,
                                                  ushort_t* __restrict__ hi,
                                                  ushort_t* __restrict__ lo, int n4)
{
    const int i = blockIdx.x * 256 + threadIdx.x;
    if (i >= n4) return;
    float4 vf = ((const float4*)src)[i];
    ushort_t h0 = f2bf(vf.x), h1 = f2bf(vf.y), h2 = f2bf(vf.z), h3 = f2bf(vf.w);
    ushort4 hv = make_ushort4(h0, h1, h2, h3);
    ushort4 lv = make_ushort4(f2bf(vf.x - bf2f(h0)), f2bf(vf.y - bf2f(h1)),
                              f2bf(vf.z - bf2f(h2)), f2bf(vf.w - bf2f(h3)));
    ((ushort4*)hi)[i] = hv;
    ((ushort4*)lo)[i] = lv;
}

// ---------------- conversion + transpose: W [K][N] fp32 -> [N][K] hi/lo bf16 ----------------
__global__ __launch_bounds__(256) void conv_split_T(const float* __restrict__ W,
                                                    ushort_t* __restrict__ hiT,
                                                    ushort_t* __restrict__ loT,
                                                    int K, int N)
{
    __shared__ ushort_t th[32][33], tl[32][33];
    const int n0 = blockIdx.x * 32, k0 = blockIdx.y * 32;
    const int tid = threadIdx.x;
    const int r = tid >> 3, c4 = (tid & 7) * 4;
    float4 vf = *(const float4*)&W[(size_t)(k0 + r) * N + n0 + c4];
    float vv[4] = {vf.x, vf.y, vf.z, vf.w};
#pragma unroll
    for (int j = 0; j < 4; ++j) {
        ushort_t h = f2bf(vv[j]);
        th[r][c4 + j] = h;
        tl[r][c4 + j] = f2bf(vv[j] - bf2f(h));
    }
    __syncthreads();
    ushort4 oh = make_ushort4(th[c4 + 0][r], th[c4 + 1][r], th[c4 + 2][r], th[c4 + 3][r]);
    ushort4 ol = make_ushort4(tl[c4 + 0][r], tl[c4 + 1][r], tl[c4 + 2][r], tl[c4 + 3][r]);
    *(ushort4*)&hiT[(size_t)(n0 + r) * K + k0 + c4] = oh;
    *(ushort4*)&loT[(size_t)(n0 + r) * K + k0 + c4] = ol;
}

// ---------------- split-bf16 MFMA mainloop: C[128][128] += A[128][K] * B^T[128][K]^T ----------------
// A-frag: lane holds A[m=lane&15][k=quad*8+j]; B-frag: B[k=quad*8+j][n=lane&15]
// (B stored transposed [n][k] so both use identical contiguous-k addressing)
// C/D: col=lane&15, row=quad*4+reg  [verified m89/m91]
__device__ __forceinline__ void mfma_mainloop(const ushort_t* __restrict__ Ah,
                                              const ushort_t* __restrict__ Al,
                                              const ushort_t* __restrict__ Bh,
                                              const ushort_t* __restrict__ Bl,
                                              int K, int m0, int n0,
                                              ushort_t* smem, f32x4 (&acc)[4][4])
{
    ushort_t* sAh = smem;
    ushort_t* sAl = smem + 128 * LK;
    ushort_t* sBh = smem + 2 * 128 * LK;
    ushort_t* sBl = smem + 3 * 128 * LK;
    const int tid = threadIdx.x;
    const int lane = tid & 63;
    const int w = tid >> 6;
    const int wm = (w >> 1) * 64, wn = (w & 1) * 64;
    const int c16 = lane & 15;
    const int q8 = (lane >> 4) * 8;

    const ushort_t* gAh = Ah + (size_t)m0 * K;
    const ushort_t* gAl = Al + (size_t)m0 * K;
    const ushort_t* gBh = Bh + (size_t)n0 * K;
    const ushort_t* gBl = Bl + (size_t)n0 * K;

    for (int k0 = 0; k0 < K; k0 += 32) {
        __syncthreads();
#pragma unroll
        for (int cc = 0; cc < 2; ++cc) {
            const int c = tid + cc * 256;
            const int row = c >> 2, part = c & 3;
            const size_t goff = (size_t)row * K + k0 + part * 8;
            const int loff = row * LK + part * 8;
            *(float4*)&sAh[loff] = *(const float4*)&gAh[goff];
            *(float4*)&sAl[loff] = *(const float4*)&gAl[goff];
            *(float4*)&sBh[loff] = *(const float4*)&gBh[goff];
            *(float4*)&sBl[loff] = *(const float4*)&gBl[goff];
        }
        __syncthreads();
        bf16x8 ah[4], al[4];
#pragma unroll
        for (int mt = 0; mt < 4; ++mt) {
            ah[mt] = *(const bf16x8*)&sAh[(wm + mt * 16 + c16) * LK + q8];
            al[mt] = *(const bf16x8*)&sAl[(wm + mt * 16 + c16) * LK + q8];
        }
#pragma unroll
        for (int nt = 0; nt < 4; ++nt) {
            bf16x8 bh = *(const bf16x8*)&sBh[(wn + nt * 16 + c16) * LK + q8];
            bf16x8 bl = *(const bf16x8*)&sBl[(wn + nt * 16 + c16) * LK + q8];
#pragma unroll
            for (int mt = 0; mt < 4; ++mt) {
                acc[mt][nt] = __builtin_amdgcn_mfma_f32_16x16x32_bf16(ah[mt], bh, acc[mt][nt], 0, 0, 0);
                acc[mt][nt] = __builtin_amdgcn_mfma_f32_16x16x32_bf16(al[mt], bh, acc[mt][nt], 0, 0, 0);
                acc[mt][nt] = __builtin_amdgcn_mfma_f32_16x16x32_bf16(ah[mt], bl, acc[mt][nt], 0, 0, 0);
            }
        }
    }
}

// ---------------- GEMM 1: qkv = x @ Wqkv + bqkv -> scatter q,k,v [B,H,T,DK] ----------------
__global__ __launch_bounds__(256) void qkv_mfma(const ushort_t* __restrict__ xh,
                                                const ushort_t* __restrict__ xl,
                                                const ushort_t* __restrict__ wh,
                                                const ushort_t* __restrict__ wl,
                                                const float* __restrict__ bias,
                                                float* __restrict__ q,
                                                float* __restrict__ k,
                                                float* __restrict__ v)
{
    __shared__ ushort_t smem[4 * 128 * LK];
    f32x4 acc[4][4] = {};
    const int m0 = blockIdx.y * 128, n0 = blockIdx.x * 128;
    mfma_mainloop(xh, xl, wh, wl, DD, m0, n0, smem, acc);

    const int tid = threadIdx.x, lane = tid & 63, w = tid >> 6;
    const int wm = (w >> 1) * 64, wn = (w & 1) * 64;
    const int c16 = lane & 15, rq = (lane >> 4) * 4;
#pragma unroll
    for (int mt = 0; mt < 4; ++mt)
#pragma unroll
        for (int nt = 0; nt < 4; ++nt)
#pragma unroll
            for (int r = 0; r < 4; ++r) {
                const int m = m0 + wm + mt * 16 + rq + r;
                const int n = n0 + wn + nt * 16 + c16;
                const float val = acc[mt][nt][r] + bias[n];
                const int bidx = m >> 9, t = m & (TT - 1);
                const int sel = n >> 10, d = n & (DD - 1);
                const int h = d >> 6, dk = d & (DKK - 1);
                float* dst = (sel == 0) ? q : (sel == 1) ? k : v;
                dst[((((size_t)bidx * HH + h) * TT + t) * DKK) + dk] = val;
            }
}

// ---------------- GEMM 2: out = ctx @ Wo + bo ----------------
__global__ __launch_bounds__(256) void out_mfma(const ushort_t* __restrict__ ah,
                                                const ushort_t* __restrict__ al,
                                                const ushort_t* __restrict__ wh,
                                                const ushort_t* __restrict__ wl,
                                                const float* __restrict__ bias,
                                                float* __restrict__ out)
{
    __shared__ ushort_t smem[4 * 128 * LK];
    f32x4 acc[4][4] = {};
    const int m0 = blockIdx.y * 128, n0 = blockIdx.x * 128;
    mfma_mainloop(ah, al, wh, wl, DD, m0, n0, smem, acc);

    const int tid = threadIdx.x, lane = tid & 63, w = tid >> 6;
    const int wm = (w >> 1) * 64, wn = (w & 1) * 64;
    const int c16 = lane & 15, rq = (lane >> 4) * 4;
#pragma unroll
    for (int mt = 0; mt < 4; ++mt)
#pragma unroll
        for (int nt = 0; nt < 4; ++nt)
#pragma unroll
            for (int r = 0; r < 4; ++r) {
                const int m = m0 + wm + mt * 16 + rq + r;
                const int n = n0 + wn + nt * 16 + c16;
                out[(size_t)m * DD + n] = acc[mt][nt][r] + bias[n];
            }
}

// ---------------- Fused windowed attention, flash-style, 64-row tiles ----------------
__global__ __launch_bounds__(256) void attn_fused(const float* __restrict__ q,
                                                  const float* __restrict__ k,
                                                  const float* __restrict__ v,
                                                  const float* __restrict__ rel,
                                                  float* __restrict__ attn_out,
                                                  float* __restrict__ ctx)
{
    const int it = blockIdx.x;
    const int h  = blockIdx.y;
    const int b  = blockIdx.z;
    const int i0 = it * TILE_M;
    int jbase = i0 - WIN; if (jbase < 0) jbase = 0; if (jbase > TT - JSPAN) jbase = TT - JSPAN;

    const int tid = threadIdx.x;
    const int tx = tid & 15, ty = tid >> 4;

    __shared__ float smem[2 * TILE_M * LSTR + 1024];
    float* buf0   = smem;
    float* buf1   = smem + TILE_M * LSTR;
    float* bias_s = smem + 2 * TILE_M * LSTR;

    const size_t bh = (size_t)b * HH + h;
    const float* qb = q + (bh * TT + i0) * DKK;
    const float* kb = k + bh * TT * DKK;
    const float* vb = v + bh * TT * DKK;
    float* arow = attn_out + (bh * TT + i0) * TT;

    {
        const float4 z = make_float4(0.f, 0.f, 0.f, 0.f);
        for (int idx = tid; idx < TILE_M * 48; idx += 256) {
            const int r  = idx / 48;
            const int c4 = idx - r * 48;
            const int col = (c4 * 4 < jbase) ? c4 * 4 : c4 * 4 + JSPAN;
            *(float4*)&arow[(size_t)r * TT + col] = z;
        }
    }

    for (int idx = tid; idx < 2 * MAXLEN - 1; idx += 256)
        bias_s[idx] = rel[(size_t)idx * HH + h];

    {
        const int d = tid & 63, r0 = tid >> 6;
#pragma unroll
        for (int ii = 0; ii < 16; ++ii) {
            const int i = r0 + ii * 4;
            buf0[d * LSTR + i] = qb[(size_t)i * DKK + d];
        }
    }
    __syncthreads();

    float s[NCHUNK][4][4];
#pragma unroll 1
    for (int c = 0; c < NCHUNK; ++c) {
        if (c > 0) __syncthreads();
        {
            const int d = tid & 63, r0 = tid >> 6;
#pragma unroll
            for (int jj = 0; jj < 16; ++jj) {
                const int j = r0 + jj * 4;
                buf1[d * LSTR + j] = kb[(size_t)(jbase + c * 64 + j) * DKK + d];
            }
        }
        __syncthreads();
        float acc[4][4] = {};
#pragma unroll
        for (int kk = 0; kk < 64; ++kk) {
            float4 a  = *(const float4*)&buf0[kk * LSTR + ty * 4];
            float4 b4 = *(const float4*)&buf1[kk * LSTR + tx * 4];
            float av[4] = {a.x, a.y, a.z, a.w};
            float bv[4] = {b4.x, b4.y, b4.z, b4.w};
#pragma unroll
            for (int r = 0; r < 4; ++r)
#pragma unroll
                for (int ccx = 0; ccx < 4; ++ccx)
                    acc[r][ccx] += av[r] * bv[ccx];
        }
#pragma unroll
        for (int r = 0; r < 4; ++r) {
            const int i = i0 + ty * 4 + r;
#pragma unroll
            for (int ccx = 0; ccx < 4; ++ccx) {
                const int j = jbase + c * 64 + tx * 4 + ccx;
                const int d = j - i;
                const float val = acc[r][ccx] * 0.125f + bias_s[d + MAXLEN - 1];
                s[c][r][ccx] = (d >= -WIN && d <= WIN) ? val : -INFINITY;
            }
        }
    }

    float mrow[4], sumr[4];
#pragma unroll
    for (int r = 0; r < 4; ++r) {
        float m = -INFINITY;
#pragma unroll
        for (int c = 0; c < NCHUNK; ++c)
#pragma unroll
            for (int ccx = 0; ccx < 4; ++ccx) m = fmaxf(m, s[c][r][ccx]);
        mrow[r] = m;
    }
#pragma unroll
    for (int off = 1; off < 16; off <<= 1)
#pragma unroll
        for (int r = 0; r < 4; ++r)
            mrow[r] = fmaxf(mrow[r], __shfl_xor(mrow[r], off));
#pragma unroll
    for (int r = 0; r < 4; ++r) sumr[r] = 0.f;
#pragma unroll
    for (int c = 0; c < NCHUNK; ++c)
#pragma unroll
        for (int r = 0; r < 4; ++r)
#pragma unroll
            for (int ccx = 0; ccx < 4; ++ccx) {
                const float e = __expf(s[c][r][ccx] - mrow[r]);
                s[c][r][ccx] = e;
                sumr[r] += e;
            }
#pragma unroll
    for (int off = 1; off < 16; off <<= 1)
#pragma unroll
        for (int r = 0; r < 4; ++r)
            sumr[r] += __shfl_xor(sumr[r], off);
    float invr[4];
#pragma unroll
    for (int r = 0; r < 4; ++r) invr[r] = 1.0f / sumr[r];
#pragma unroll
    for (int c = 0; c < NCHUNK; ++c)
#pragma unroll
        for (int r = 0; r < 4; ++r)
#pragma unroll
            for (int ccx = 0; ccx < 4; ++ccx)
                s[c][r][ccx] *= invr[r];

    float o[4][4] = {};
#pragma unroll 1
    for (int c = 0; c < NCHUNK; ++c) {
        __syncthreads();
#pragma unroll
        for (int r = 0; r < 4; ++r) {
            float4 pv = make_float4(s[c][r][0], s[c][r][1], s[c][r][2], s[c][r][3]);
            *(float4*)&arow[(size_t)(ty * 4 + r) * TT + jbase + c * 64 + tx * 4] = pv;
#pragma unroll
            for (int ccx = 0; ccx < 4; ++ccx)
                buf0[(tx * 4 + ccx) * LSTR + ty * 4 + r] = s[c][r][ccx];
        }
        {
            const int d4 = (tid & 15) * 4, r0 = tid >> 4;
#pragma unroll
            for (int jj = 0; jj < 4; ++jj) {
                const int j = r0 + jj * 16;
                *(float4*)&buf1[j * LSTR + d4] =
                    *(const float4*)&vb[(size_t)(jbase + c * 64 + j) * DKK + d4];
            }
        }
        __syncthreads();
#pragma unroll
        for (int kk = 0; kk < 64; ++kk) {
            float4 a  = *(const float4*)&buf0[kk * LSTR + ty * 4];
            float4 b4 = *(const float4*)&buf1[kk * LSTR + tx * 4];
            float av[4] = {a.x, a.y, a.z, a.w};
            float bv[4] = {b4.x, b4.y, b4.z, b4.w};
#pragma unroll
            for (int r = 0; r < 4; ++r)
#pragma unroll
                for (int ccx = 0; ccx < 4; ++ccx)
                    o[r][ccx] += av[r] * bv[ccx];
        }
    }

#pragma unroll
    for (int r = 0; r < 4; ++r) {
        float4 ov = make_float4(o[r][0], o[r][1], o[r][2], o[r][3]);
        *(float4*)&ctx[(((size_t)b * TT + i0 + ty * 4 + r) * HH + h) * DKK + tx * 4] = ov;
    }
}

extern "C" void kernel_launch(void* const* d_in, const int* in_sizes, int n_in,
                              void* d_out, int out_size, void* d_ws, size_t ws_size,
                              hipStream_t stream)
{
    const float* x    = (const float*)d_in[0];
    const float* Wqkv = (const float*)d_in[1];
    const float* bqkv = (const float*)d_in[2];
    const float* Wo   = (const float*)d_in[3];
    const float* bo   = (const float*)d_in[4];
    const float* rel  = (const float*)d_in[5];

    float* out  = (float*)d_out;
    float* attn = out + (size_t)BB * TT * DD;

    const size_t per = (size_t)BB * HH * TT * DKK;   // 8,388,608
    float* q = (float*)d_ws;
    float* k = q + per;
    float* v = k + per;
    ushort_t* xh = (ushort_t*)(v + per);
    ushort_t* xl = xh + per;
    float* ctx = (float*)xh;                 // aliases xh/xl (dead after qkv_mfma)
    ushort_t* Wqh = (ushort_t*)(xl + per);
    ushort_t* Wql = Wqh + (size_t)DD * 3 * DD;
    ushort_t* cxh = (ushort_t*)q;            // aliases q (dead after attn)
    ushort_t* cxl = (ushort_t*)k;            // aliases k (dead after attn)
    ushort_t* Woh = (ushort_t*)v;            // aliases v (dead after attn)
    ushort_t* Wol = Woh + (size_t)DD * DD;

    const int n4x = BB * TT * DD / 4;        // 2,097,152

    conv_split<<<dim3((n4x + 255) / 256), 256, 0, stream>>>(x, xh, xl, n4x);
    conv_split_T<<<dim3(3 * DD / 32, DD / 32), 256, 0, stream>>>(Wqkv, Wqh, Wql, DD, 3 * DD);
    qkv_mfma<<<dim3(3 * DD / 128, BB * TT / 128), 256, 0, stream>>>(xh, xl, Wqh, Wql, bqkv, q, k, v);
    attn_fused<<<dim3(TT / TILE_M, HH, BB), 256, 0, stream>>>(q, k, v, rel, attn, ctx);
    conv_split<<<dim3((n4x + 255) / 256), 256, 0, stream>>>(ctx, cxh, cxl, n4x);
    conv_split_T<<<dim3(DD / 32, DD / 32), 256, 0, stream>>>(Wo, Woh, Wol, DD, DD);
    out_mfma<<<dim3(DD / 128, BB * TT / 128), 256, 0, stream>>>(cxh, cxl, Woh, Wol, bo, out);
}